// Round 1
// baseline (174.786 us; speedup 1.0000x reference)
//
#include <hip/hip_runtime.h>
#include <hip/hip_bf16.h>

#define N_ROWS 16384
#define DIM 128

constexpr float INV_T  = 1.0f / 0.07f;            // 14.2857...
constexpr float LOG2E  = 1.4426950408889634f;
constexpr float C1     = INV_T * LOG2E;           // logit->exp2 scale

typedef short bf16x8 __attribute__((ext_vector_type(8)));
typedef float f32x4  __attribute__((ext_vector_type(4)));

__device__ __forceinline__ ushort f2bf(float x) {
    unsigned u = __float_as_uint(x);
    u += 0x7fffu + ((u >> 16) & 1u);              // round-to-nearest-even
    return (ushort)(u >> 16);
}

// ---------------------------------------------------------------------------
// Kernel 1: L2-normalize rows of A and P -> bf16; exact fp32 diagonal logit.
// One wave per row (128 elems = 2 per lane). 4 waves per block.
// ---------------------------------------------------------------------------
__global__ __launch_bounds__(256) void norm_kernel(
    const float* __restrict__ A, const float* __restrict__ P,
    ushort* __restrict__ a16, ushort* __restrict__ p16,
    float* __restrict__ diag)
{
    int row  = blockIdx.x * 4 + (threadIdx.x >> 6);
    int lane = threadIdx.x & 63;
    float2 av = *(const float2*)(A + (size_t)row * DIM + lane * 2);
    float2 pv = *(const float2*)(P + (size_t)row * DIM + lane * 2);
    float ssa = av.x * av.x + av.y * av.y;
    float ssp = pv.x * pv.x + pv.y * pv.y;
    float dp  = av.x * pv.x + av.y * pv.y;
    #pragma unroll
    for (int m = 1; m < 64; m <<= 1) {
        ssa += __shfl_xor(ssa, m);
        ssp += __shfl_xor(ssp, m);
        dp  += __shfl_xor(dp,  m);
    }
    float sa = 1.0f / fmaxf(sqrtf(ssa), 1e-12f);
    float sp = 1.0f / fmaxf(sqrtf(ssp), 1e-12f);
    if (lane == 0) diag[row] = dp * sa * sp * INV_T;
    ushort2 a2, p2;
    a2.x = f2bf(av.x * sa); a2.y = f2bf(av.y * sa);
    p2.x = f2bf(pv.x * sp); p2.y = f2bf(pv.y * sp);
    *(ushort2*)(a16 + (size_t)row * DIM + lane * 2) = a2;
    *(ushort2*)(p16 + (size_t)row * DIM + lane * 2) = p2;
}

// ---------------------------------------------------------------------------
// Kernel 2: logits = a_n @ p_n^T / T ; accumulate per-row sum of
// exp(logit - B) with FIXED bound B = 1/T (|cos| <= 1) -> no online max.
// Block: 4 waves, BM=128 rows (A frags in registers).
// Columns: staged 64 at a time in LDS; column range split 4 ways over blocks.
// Partial row sums merged via atomicAdd (m is a shared constant).
// ---------------------------------------------------------------------------
#define BM 128
#define BCOL 64
#define COLSPLIT 4
#define COLS_PER (N_ROWS / COLSPLIT)     // 4096
#define LDSPITCH 136                      // 128 + 8 bf16 pad -> 68-dword stride

__global__ __launch_bounds__(256) void lse_kernel(
    const ushort* __restrict__ a16, const ushort* __restrict__ p16,
    float* __restrict__ s_accum)
{
    __shared__ ushort ptile[BCOL][LDSPITCH];

    int rowblk = blockIdx.x >> 2;
    int colseg = blockIdx.x & 3;
    int wave = threadIdx.x >> 6;
    int lane = threadIdx.x & 63;
    int l16  = lane & 15, lhi = lane >> 4;
    int row0 = rowblk * BM + wave * 32;

    // A fragments: 2 row-tiles x 4 k-frags, each lane 8 contiguous bf16.
    bf16x8 afrag[2][4];
    #pragma unroll
    for (int t = 0; t < 2; ++t)
        #pragma unroll
        for (int kf = 0; kf < 4; ++kf)
            afrag[t][kf] = *(const bf16x8*)(
                a16 + (size_t)(row0 + t * 16 + l16) * DIM + kf * 32 + lhi * 8);

    float s[2][4] = {{0.f,0.f,0.f,0.f},{0.f,0.f,0.f,0.f}};
    int col0 = colseg * COLS_PER;

    for (int jt = 0; jt < COLS_PER; jt += BCOL) {
        __syncthreads();
        // stage 64 p-rows (cols of logits) into LDS: 1024 chunks of 8 bf16
        #pragma unroll
        for (int c = 0; c < 4; ++c) {
            int chunk = threadIdx.x + c * 256;
            int r = chunk >> 4, k8 = chunk & 15;
            *(bf16x8*)(&ptile[r][k8 * 8]) =
                *(const bf16x8*)(p16 + (size_t)(col0 + jt + r) * DIM + k8 * 8);
        }
        __syncthreads();

        #pragma unroll
        for (int st = 0; st < 4; ++st) {
            bf16x8 bfrag[4];
            #pragma unroll
            for (int kf = 0; kf < 4; ++kf)
                bfrag[kf] = *(const bf16x8*)(
                    &ptile[st * 16 + l16][kf * 32 + lhi * 8]);
            #pragma unroll
            for (int t = 0; t < 2; ++t) {
                f32x4 acc = {0.f, 0.f, 0.f, 0.f};
                #pragma unroll
                for (int kf = 0; kf < 4; ++kf)
                    acc = __builtin_amdgcn_mfma_f32_16x16x32_bf16(
                        afrag[t][kf], bfrag[kf], acc, 0, 0, 0);
                #pragma unroll
                for (int r = 0; r < 4; ++r)
                    s[t][r] += exp2f(fmaf(acc[r], C1, -C1));
            }
        }
    }

    // combine the 16 column-lanes of each row, then one atomicAdd per row
    #pragma unroll
    for (int t = 0; t < 2; ++t)
        #pragma unroll
        for (int r = 0; r < 4; ++r) {
            float v = s[t][r];
            v += __shfl_xor(v, 1, 16);
            v += __shfl_xor(v, 2, 16);
            v += __shfl_xor(v, 4, 16);
            v += __shfl_xor(v, 8, 16);
            if (l16 == 0)
                atomicAdd(&s_accum[row0 + t * 16 + lhi * 4 + r], v);
        }
}

// ---------------------------------------------------------------------------
// Kernel 3: loss = mean( B + ln(s_i) - diag_i )
// ---------------------------------------------------------------------------
__global__ __launch_bounds__(256) void finalize_kernel(
    const float* __restrict__ s_accum, const float* __restrict__ diag,
    float* __restrict__ out)
{
    float acc = 0.f;
    for (int i = threadIdx.x; i < N_ROWS; i += 256)
        acc += logf(s_accum[i]) + INV_T - diag[i];
    #pragma unroll
    for (int m = 1; m < 64; m <<= 1) acc += __shfl_xor(acc, m);
    __shared__ float wsum[4];
    if ((threadIdx.x & 63) == 0) wsum[threadIdx.x >> 6] = acc;
    __syncthreads();
    if (threadIdx.x == 0)
        out[0] = (wsum[0] + wsum[1] + wsum[2] + wsum[3]) / (float)N_ROWS;
}

// ---------------------------------------------------------------------------
extern "C" void kernel_launch(void* const* d_in, const int* in_sizes, int n_in,
                              void* d_out, int out_size, void* d_ws, size_t ws_size,
                              hipStream_t stream)
{
    const float* A = (const float*)d_in[0];   // anchors
    const float* P = (const float*)d_in[1];   // positives
    float* out = (float*)d_out;

    char* ws = (char*)d_ws;
    ushort* a16    = (ushort*)ws;                                  // 4 MB
    ushort* p16    = (ushort*)(ws + (size_t)4 * 1024 * 1024);      // 4 MB
    float*  diag   = (float*)(ws + (size_t)8 * 1024 * 1024);       // 64 KB
    float*  s_acc  = (float*)(ws + (size_t)8 * 1024 * 1024 + 65536);

    hipMemsetAsync(s_acc, 0, N_ROWS * sizeof(float), stream);
    norm_kernel<<<N_ROWS / 4, 256, 0, stream>>>(A, P, a16, p16, diag);
    lse_kernel<<<(N_ROWS / BM) * COLSPLIT, 256, 0, stream>>>(a16, p16, s_acc);
    finalize_kernel<<<1, 256, 0, stream>>>(s_acc, diag, out);
}